// Round 6
// baseline (623.375 us; speedup 1.0000x reference)
//
#include <hip/hip_runtime.h>

typedef _Float16 half8v __attribute__((ext_vector_type(8)));
typedef float    f32x4  __attribute__((ext_vector_type(4)));
typedef unsigned short ushort_t;

// ---------- helpers ----------
__device__ __forceinline__ unsigned short f2h(float f) {
  _Float16 h = (_Float16)f;                  // RNE, native v_cvt_f16_f32
  return __builtin_bit_cast(unsigned short, h);
}
__device__ __forceinline__ unsigned f2h2(float lo, float hi) {
  return (unsigned)f2h(lo) | ((unsigned)f2h(hi) << 16);
}
__device__ __forceinline__ float lin14(int i) {
  double s = 1.0 / 14.0, stop = 1.0 - s;
  double step = (stop - s) / 13.0;
  return (float)((i == 13) ? stop : s + i * step);
}
__device__ __forceinline__ float lin10(int i) {
  double st = 1.0 / 9.0;
  return (float)((i == 9) ? 1.0 : i * st);
}
__device__ __forceinline__ float wave_sum(float v) {
  #pragma unroll
  for (int o = 32; o; o >>= 1) v += __shfl_xor(v, o, 64);
  return v;
}
__device__ __forceinline__ float wave_max(float v) {
  #pragma unroll
  for (int o = 32; o; o >>= 1) v = fmaxf(v, __shfl_xor(v, o, 64));
  return v;
}
__device__ __forceinline__ float blk_sum(float v, float* red) {
  v = wave_sum(v);
  if ((threadIdx.x & 63) == 0) red[threadIdx.x >> 6] = v;
  __syncthreads();
  v = red[0] + red[1] + red[2] + red[3];
  __syncthreads();
  return v;
}
__device__ __forceinline__ float blk_max(float v, float* red) {
  v = wave_max(v);
  if ((threadIdx.x & 63) == 0) red[threadIdx.x >> 6] = v;
  __syncthreads();
  v = fmaxf(fmaxf(red[0], red[1]), fmaxf(red[2], red[3]));
  __syncthreads();
  return v;
}

// ---------- K_F: F[100][196], pos, mus (constants) ----------
__global__ void k_F(float* __restrict__ posg, float* __restrict__ musg,
                    float* __restrict__ Fg) {
  int idx = blockIdx.x * 256 + threadIdx.x;
  if (idx < 196) { posg[2*idx] = lin14(idx / 14); posg[2*idx+1] = lin14(idx % 14); }
  if (idx < 100) { musg[2*idx] = lin10(idx / 10); musg[2*idx+1] = lin10(idx % 10); }
  if (idx < 19600) {
    int k = idx / 196, l = idx % 196;
    float mx = lin10(k / 10), my = lin10(k % 10);
    float px = lin14(l / 14), py = lin14(l % 14);
    double dx = (double)mx - (double)px, dy = (double)my - (double)py;
    double d2 = dx * dx + dy * dy;
    Fg[idx] = (float)(exp(-500.0 * d2) / (6.283185307179586 * 0.001));
  }
}

// ---------- K_A: A = F F^T + 0.5 I (f64) ----------
__global__ void k_A(const float* __restrict__ Fg, double* __restrict__ A) {
  int i = blockIdx.x, j = threadIdx.x;
  if (j < 100) {
    const float* Fi = Fg + i * 196;
    const float* Fj = Fg + j * 196;
    double s = 0.0;
    for (int l = 0; l < 196; ++l) s += (double)Fi[l] * (double)Fj[l];
    if (i == j) s += 0.5;
    A[i * 100 + j] = s;
  }
}

// ---------- K_inv v4: register-resident Gauss-Jordan, f64, SPD, 4 waves ----------
// 250 threads own 4x10 blocks (25 rb x 10 cb).  vs v3 (512 thr): half the
// barrier cost, 1/4 the publish serialization (10 writes max per thread).
// Branch-free rank-1 update via rk[k]=1+1/p, ck[k]=p-1 (exact GJ, verified
// for all 4 cases).  2 barriers/iter.
__global__ __launch_bounds__(256) void k_inv(const double* __restrict__ Ag,
                                             double* __restrict__ Ainv) {
  __shared__ double rowraw[100], colraw[100], rkv[100], ckv[100];
  int t = threadIdx.x;
  int rb = t / 10, cb = t % 10;      // t<250: rows [4rb,4rb+4), cols [10cb,10cb+10)
  bool own = t < 250;
  double a[4][10];
  if (own) {
    #pragma unroll
    for (int r = 0; r < 4; ++r)
      #pragma unroll
      for (int c = 0; c < 10; ++c)
        a[r][c] = Ag[(4 * rb + r) * 100 + 10 * cb + c];
  }
  __syncthreads();
  for (int k = 0; k < 100; ++k) {
    int krb = k >> 2, klr = k & 3;
    int kcb = k / 10, klc = k - 10 * kcb;
    if (own && rb == krb) {
      #pragma unroll
      for (int r = 0; r < 4; ++r)
        if (r == klr) {
          #pragma unroll
          for (int c = 0; c < 10; ++c) rowraw[10 * cb + c] = a[r][c];
        }
    }
    if (own && cb == kcb) {
      #pragma unroll
      for (int c = 0; c < 10; ++c)
        if (c == klc) {
          #pragma unroll
          for (int r = 0; r < 4; ++r) colraw[4 * rb + r] = a[r][c];
        }
    }
    __syncthreads();
    if (t < 100) {
      double p = rowraw[k], pinv = 1.0 / p;
      rkv[t] = (t == k) ? 1.0 + pinv : rowraw[t] * pinv;
      ckv[t] = (t == k) ? p - 1.0    : colraw[t];
    }
    __syncthreads();
    if (own) {
      double ckl[4], rkl[10];
      #pragma unroll
      for (int r = 0; r < 4; ++r) ckl[r] = ckv[4 * rb + r];
      #pragma unroll
      for (int c = 0; c < 10; ++c) rkl[c] = rkv[10 * cb + c];
      #pragma unroll
      for (int r = 0; r < 4; ++r)
        #pragma unroll
        for (int c = 0; c < 10; ++c)
          a[r][c] = fma(-ckl[r], rkl[c], a[r][c]);
    }
  }
  if (own) {
    #pragma unroll
    for (int r = 0; r < 4; ++r)
      #pragma unroll
      for (int c = 0; c < 10; ++c)
        Ainv[(4 * rb + r) * 100 + 10 * cb + c] = a[r][c];
  }
}

// ---------- K_G: Gt[n][l] = (F^T @ Ainv)^T  (transposed for coalesced k_batch) ----------
__global__ void k_G(const float* __restrict__ Fg, const double* __restrict__ Ainv,
                    float* __restrict__ Gt) {
  int l = blockIdx.x, n = threadIdx.x;
  if (n < 100) {
    double s = 0.0;
    for (int k = 0; k < 100; ++k) s += (double)Fg[k * 196 + l] * Ainv[k * 100 + n];
    Gt[n * 196 + l] = (float)s;
  }
}

// ---------- K_splitw1: W1[1024][512] f32 -> W1t[512][1024] fp16 (transposed) ----------
__global__ void k_splitw1(const float* __restrict__ W1, ushort_t* __restrict__ W1t) {
  __shared__ float t[32][33];
  int n0 = blockIdx.x * 32, k0 = blockIdx.y * 32;
  int tx = threadIdx.x, ty = threadIdx.y;   // 32 x 8
  #pragma unroll
  for (int i = 0; i < 32; i += 8)
    t[ty + i][tx] = W1[(size_t)(k0 + ty + i) * 512 + n0 + tx];
  __syncthreads();
  #pragma unroll
  for (int i = 0; i < 32; i += 8)
    W1t[(size_t)(n0 + ty + i) * 1024 + k0 + tx] = f2h(t[tx][ty + i]);
}

// ---------- K_wmT: Wm[1024][2048] f32 -> WmT[2048][1024] fp16 (transposed) ----------
__global__ void k_wmT(const float* __restrict__ Wm, ushort_t* __restrict__ WmT) {
  __shared__ float t[32][33];
  int n0 = blockIdx.x * 32, k0 = blockIdx.y * 32;
  int tx = threadIdx.x, ty = threadIdx.y;   // 32 x 8
  #pragma unroll
  for (int i = 0; i < 32; i += 8)
    t[ty + i][tx] = Wm[(size_t)(k0 + ty + i) * 2048 + n0 + tx];
  __syncthreads();
  #pragma unroll
  for (int i = 0; i < 32; i += 8)
    WmT[(size_t)(n0 + ty + i) * 1024 + k0 + tx] = f2h(t[tx][ty + i]);
}

// ---------- K_gemm1: logits = relu(x@W1 + b1) @ W2 (fused epilogue, atomic) ----------
// r5 counters: 163us, MfmaUtil 12.8%, VALUBusy 13.1%, Occ 35% -> latency-bound
// (loads issued+drained within one K-step; ~215cy wave-overlap vs ~400cy RTT).
// Fix: 2-deep register prefetch, unroll-by-2 (static P/Q sets, static buf0/1).
// Loads for tile k+2 issue at step k, LDS-write at step k+1 (~1.5 K-steps gap).
// A-staging: 2 rows x 8 cols/thread -> uint4 LDS writes (~2-way bank aliasing).
__global__ __launch_bounds__(256, 2) void k_gemm1(
    const float* __restrict__ x, const ushort_t* __restrict__ W1t,
    const float* __restrict__ b1, const float* __restrict__ W2,
    float* __restrict__ logits) {
  __shared__ __align__(16) ushort_t As[2][128 * 40];
  __shared__ __align__(16) ushort_t Bs[2][128 * 40];

  int bid  = blockIdx.x;
  int bid2 = (bid & 7) * 196 + (bid >> 3);       // XCD-contiguous chunks
  int tm = bid2 >> 2, tn = bid2 & 3;
  size_t row0 = (size_t)tm * 128;
  int n0 = tn * 128;
  int tid = threadIdx.x, lane = tid & 63;
  int wid = tid >> 6, wm = wid >> 1, wn = wid & 1;

  // stage mapping: 4 lanes/row, 8 cols (16B) each, 2 row-slabs of 64
  const float*    xp = x   + (row0 + (tid >> 2)) * 1024 + ((tid & 3) << 3);
  const ushort_t* wp = W1t + (size_t)(n0 + (tid >> 2)) * 1024 + ((tid & 3) << 3);
  int so = (tid >> 2) * 40 + ((tid & 3) << 3);

  int aro = (wm * 64 + (lane & 15)) * 40 + ((lane >> 4) << 3);
  int bro = (wn * 64 + (lane & 15)) * 40 + ((lane >> 4) << 3);

  f32x4 acc[4][4] = {};

  float4 aP[4], aQ[4]; uint4 bP[2], bQ[2];

  auto issueP = [&](int ks) {
    #pragma unroll
    for (int r = 0; r < 2; ++r) {
      aP[2*r]   = *(const float4*)(xp + ks * 32 + r * 64 * 1024);
      aP[2*r+1] = *(const float4*)(xp + ks * 32 + r * 64 * 1024 + 4);
      bP[r]     = *(const uint4*)(wp + ks * 32 + r * 64 * 1024);
    }
  };
  auto issueQ = [&](int ks) {
    #pragma unroll
    for (int r = 0; r < 2; ++r) {
      aQ[2*r]   = *(const float4*)(xp + ks * 32 + r * 64 * 1024);
      aQ[2*r+1] = *(const float4*)(xp + ks * 32 + r * 64 * 1024 + 4);
      bQ[r]     = *(const uint4*)(wp + ks * 32 + r * 64 * 1024);
    }
  };
  auto writeP = [&](int buf) {
    #pragma unroll
    for (int r = 0; r < 2; ++r) {
      uint4 w;
      w.x = f2h2(aP[2*r].x, aP[2*r].y);   w.y = f2h2(aP[2*r].z, aP[2*r].w);
      w.z = f2h2(aP[2*r+1].x, aP[2*r+1].y); w.w = f2h2(aP[2*r+1].z, aP[2*r+1].w);
      *(uint4*)&As[buf][so + r * 64 * 40] = w;
      *(uint4*)&Bs[buf][so + r * 64 * 40] = bP[r];
    }
  };
  auto writeQ = [&](int buf) {
    #pragma unroll
    for (int r = 0; r < 2; ++r) {
      uint4 w;
      w.x = f2h2(aQ[2*r].x, aQ[2*r].y);   w.y = f2h2(aQ[2*r].z, aQ[2*r].w);
      w.z = f2h2(aQ[2*r+1].x, aQ[2*r+1].y); w.w = f2h2(aQ[2*r+1].z, aQ[2*r+1].w);
      *(uint4*)&As[buf][so + r * 64 * 40] = w;
      *(uint4*)&Bs[buf][so + r * 64 * 40] = bQ[r];
    }
  };
  auto mmac = [&](int buf) {
    half8v af[4], bf[4];
    #pragma unroll
    for (int i = 0; i < 4; ++i) af[i] = *(const half8v*)&As[buf][aro + i * 16 * 40];
    #pragma unroll
    for (int i = 0; i < 4; ++i) bf[i] = *(const half8v*)&Bs[buf][bro + i * 16 * 40];
    #pragma unroll
    for (int i = 0; i < 4; ++i)
      #pragma unroll
      for (int j = 0; j < 4; ++j)
        acc[i][j] = __builtin_amdgcn_mfma_f32_16x16x32_f16(af[i], bf[j], acc[i][j], 0, 0, 0);
  };

  // prologue: tile0 -> buf0 (immediate), tile1 in flight in Q
  issueP(0);
  writeP(0);
  issueQ(1);
  __syncthreads();

  #pragma unroll 1
  for (int kp = 0; kp < 16; ++kp) {
    int e = 2 * kp;
    // step A: compute buf0 (tile e); issue e+2 -> P; write Q (tile e+1) -> buf1
    if (e < 30) issueP(e + 2);
    mmac(0);
    if (e < 31) writeQ(1);
    __syncthreads();
    // step B: compute buf1 (tile e+1); issue e+3 -> Q; write P (tile e+2) -> buf0
    if (e + 1 < 30) issueQ(e + 3);
    mmac(1);
    if (e + 1 < 31) writeP(0);
    __syncthreads();
  }

  // fused epilogue: logits partial = sum_n relu(acc + b1[n]) * W2[n]
  int cbase = n0 + wn * 64 + (lane & 15);
  float b1v[4], w2v[4];
  #pragma unroll
  for (int j = 0; j < 4; ++j) { b1v[j] = b1[cbase + j * 16]; w2v[j] = W2[cbase + j * 16]; }
  float part[4][4];
  #pragma unroll
  for (int i = 0; i < 4; ++i)
    #pragma unroll
    for (int q = 0; q < 4; ++q) {
      float s = 0.f;
      #pragma unroll
      for (int j = 0; j < 4; ++j) {
        float h = acc[i][j][q] + b1v[j];
        s += fmaxf(h, 0.f) * w2v[j];
      }
      part[i][q] = s;
    }
  #pragma unroll
  for (int off = 1; off < 16; off <<= 1)
    #pragma unroll
    for (int i = 0; i < 4; ++i)
      #pragma unroll
      for (int q = 0; q < 4; ++q)
        part[i][q] += __shfl_xor(part[i][q], off, 64);
  if ((lane & 15) == 0) {
    int rbase = (int)row0 + wm * 64 + ((lane >> 4) << 2);
    #pragma unroll
    for (int i = 0; i < 4; ++i)
      #pragma unroll
      for (int q = 0; q < 4; ++q)
        atomicAdd(&logits[rbase + i * 16 + q], part[i][q]);
  }
}

// ---------- K_batch: softmax, mu, Sigma, Sinv, r, g = Gt^T@r  (one block per b) ----------
__global__ __launch_bounds__(256) void k_batch(
    const float* __restrict__ logits, const unsigned char* __restrict__ mask,
    const float* __restrict__ b2, const float* __restrict__ pos,
    const float* __restrict__ mus, const float* __restrict__ Gt,
    float* __restrict__ g_out) {
  __shared__ float red[4];
  __shared__ float rsh[100];
  int b = blockIdx.x, tid = threadIdx.x;
  bool act = tid < 196;
  float lg = -1e30f;
  if (act) {
    lg = logits[b * 196 + tid] + b2[0];
    if (mask[b * 196 + tid]) lg = -1e9f;
  }
  float m = blk_max(lg, red);
  float e = act ? expf(lg - m) : 0.f;
  float Z = blk_sum(e, red);
  float pv = e / Z;
  float px = act ? pos[2 * tid] : 0.f, py = act ? pos[2 * tid + 1] : 0.f;
  float mux = blk_sum(pv * px, red);
  float muy = blk_sum(pv * py, red);
  float dx = px - mux, dy = py - muy;
  float sxx = blk_sum(pv * dx * dx, red);
  float sxy = blk_sum(pv * dx * dy, red);
  float syy = blk_sum(pv * dy * dy, red);
  float aa = (sxx + 1e-6f) + 1e-3f;
  float bb = sxy;
  float dd = (syy + 1e-6f) + 1e-3f;
  float det = aa * dd - bb * bb;
  float scale = 1.f / (6.2831853071795864f * sqrtf(det));
  if (tid < 100) {
    float dmx = mux - mus[2 * tid], dmy = muy - mus[2 * tid + 1];
    float quad = (dd * dmx * dmx - 2.f * bb * dmx * dmy + aa * dmy * dmy) / det;
    rsh[tid] = expf(-0.5f * quad) * scale;
  }
  __syncthreads();
  if (act) {
    float s = 0.f;
    #pragma unroll 4
    for (int n = 0; n < 100; ++n) s = fmaf(Gt[n * 196 + tid], rsh[n], s);
    g_out[b * 196 + tid] = s;
  }
}

// ---------- K_ctx: ctxh[b,d] = (fp16) sum_l x[b,l,d] * g[b,l] ----------
__global__ __launch_bounds__(256) void k_ctx(const float* __restrict__ x,
                                             const float* __restrict__ g,
                                             ushort_t* __restrict__ ctxh) {
  int b = blockIdx.y, seg = blockIdx.x, tid = threadIdx.x;
  __shared__ float gs[196];
  if (tid < 196) gs[tid] = g[b * 196 + tid];
  __syncthreads();
  int d = seg * 256 + tid;
  const float* xp = x + (size_t)b * 200704 + d;
  float acc = 0.f;
  #pragma unroll 8
  for (int l = 0; l < 196; ++l) acc = fmaf(xp[(size_t)l * 1024], gs[l], acc);
  ctxh[b * 1024 + d] = f2h(acc);
}

// ---------- K_out2: out = ctxh @ WmT^T + bm   (fp16 MFMA, 64x128 tile, BK=32) ----------
__global__ __launch_bounds__(256, 2) void k_out2(
    const ushort_t* __restrict__ ctxh, const ushort_t* __restrict__ WmT,
    const float* __restrict__ bm, float* __restrict__ out) {
  __shared__ __align__(16) ushort_t As[2][64 * 40];
  __shared__ __align__(16) ushort_t Bs[2][128 * 40];
  int n0 = blockIdx.x * 128;
  int m0 = blockIdx.y * 64;
  int tid = threadIdx.x, lane = tid & 63;
  int wid = tid >> 6, wm = wid >> 1, wn = wid & 1;

  int arow = tid >> 2, aseg = (tid & 3) << 3;          // 64 rows x 4 segs of 8
  const ushort_t* ap = ctxh + (m0 + arow) * 1024 + aseg;
  int aso = arow * 40 + aseg;
  int brow = tid >> 1, bsh = (tid & 1) << 4;           // 128 rows x 2 halves of 16
  const ushort_t* bp = WmT + (size_t)(n0 + brow) * 1024 + bsh;
  int bso = brow * 40 + bsh;

  int aro = (wm * 32 + (lane & 15)) * 40 + ((lane >> 4) << 3);
  int bro = (wn * 64 + (lane & 15)) * 40 + ((lane >> 4) << 3);

  f32x4 acc[2][4] = {};
  uint4 a4, b4[2];
  a4 = *(const uint4*)ap;
  b4[0] = *(const uint4*)bp; b4[1] = *(const uint4*)(bp + 8);
  *(uint4*)&As[0][aso] = a4;
  *(uint4*)&Bs[0][bso] = b4[0]; *(uint4*)&Bs[0][bso + 8] = b4[1];
  __syncthreads();

  int cur = 0;
  for (int ks = 0; ks < 32; ++ks) {
    if (ks < 31) {
      a4 = *(const uint4*)(ap + (ks + 1) * 32);
      b4[0] = *(const uint4*)(bp + (ks + 1) * 32);
      b4[1] = *(const uint4*)(bp + (ks + 1) * 32 + 8);
    }
    half8v af[2], bf[4];
    #pragma unroll
    for (int i = 0; i < 2; ++i) af[i] = *(const half8v*)&As[cur][aro + i * 16 * 40];
    #pragma unroll
    for (int j = 0; j < 4; ++j) bf[j] = *(const half8v*)&Bs[cur][bro + j * 16 * 40];
    #pragma unroll
    for (int i = 0; i < 2; ++i)
      #pragma unroll
      for (int j = 0; j < 4; ++j)
        acc[i][j] = __builtin_amdgcn_mfma_f32_16x16x32_f16(af[i], bf[j], acc[i][j], 0, 0, 0);
    if (ks < 31) {
      *(uint4*)&As[cur ^ 1][aso] = a4;
      *(uint4*)&Bs[cur ^ 1][bso] = b4[0]; *(uint4*)&Bs[cur ^ 1][bso + 8] = b4[1];
    }
    __syncthreads();
    cur ^= 1;
  }

  int rbase = m0 + wm * 32 + ((lane >> 4) << 2);
  int cbase = n0 + wn * 64 + (lane & 15);
  #pragma unroll
  for (int j = 0; j < 4; ++j) {
    float bmv = bm[cbase + j * 16];
    #pragma unroll
    for (int i = 0; i < 2; ++i)
      #pragma unroll
      for (int q = 0; q < 4; ++q)
        out[(size_t)(rbase + i * 16 + q) * 2048 + cbase + j * 16] = acc[i][j][q] + bmv;
  }
}

// ---------- launch ----------
extern "C" void kernel_launch(void* const* d_in, const int* in_sizes, int n_in,
                              void* d_out, int out_size, void* d_ws, size_t ws_size,
                              hipStream_t stream) {
  const float* x  = (const float*)d_in[0];
  const unsigned char* xmask = (const unsigned char*)d_in[1];
  const float* W1 = (const float*)d_in[2];
  const float* b1 = (const float*)d_in[3];
  const float* W2 = (const float*)d_in[4];
  const float* b2 = (const float*)d_in[5];
  const float* Wm = (const float*)d_in[6];
  const float* bm = (const float*)d_in[7];
  float* out = (float*)d_out;

  char* ws = (char*)d_ws;
  float*    Fg     = (float*)(ws + 0);          // 78400 B
  double*   Ainv   = (double*)(ws + 78400);     // 80000 B
  double*   Atmp   = (double*)(ws + 158400);    // 80000 B
  float*    posg   = (float*)(ws + 238400);     // 1568 B
  float*    musg   = (float*)(ws + 239968);     // 800 B
  float*    Gt     = (float*)(ws + 240768);     // 78400 B
  float*    logits = (float*)(ws + 319168);     // 200704 B
  float*    gbuf   = (float*)(ws + 519872);     // 200704 B
  ushort_t* ctxh   = (ushort_t*)(ws + 720576);  // 524288 B
  ushort_t* W1t    = (ushort_t*)(ws + 1244864); // 1048576 B
  ushort_t* WmT    = (ushort_t*)(ws + 2293440); // 4194304 B  (total ~6.2 MB)

  k_F<<<77, 256, 0, stream>>>(posg, musg, Fg);
  k_A<<<100, 128, 0, stream>>>(Fg, Atmp);
  k_inv<<<1, 256, 0, stream>>>(Atmp, Ainv);
  k_G<<<196, 128, 0, stream>>>(Fg, Ainv, Gt);
  k_splitw1<<<dim3(16, 32), dim3(32, 8), 0, stream>>>(W1, W1t);
  k_wmT<<<dim3(64, 32), dim3(32, 8), 0, stream>>>(Wm, WmT);
  hipMemsetAsync(logits, 0, 200704, stream);
  k_gemm1<<<1568, 256, 0, stream>>>(x, W1t, b1, W2, logits);
  k_batch<<<256, 256, 0, stream>>>(logits, xmask, b2, posg, musg, Gt, gbuf);
  k_ctx<<<dim3(4, 256), 256, 0, stream>>>(x, gbuf, ctxh);
  k_out2<<<dim3(16, 4), 256, 0, stream>>>(ctxh, WmT, bm, out);
}

// Round 11
// 620.782 us; speedup vs baseline: 1.0042x; 1.0042x over previous
//
#include <hip/hip_runtime.h>

typedef _Float16 half8v __attribute__((ext_vector_type(8)));
typedef float    f32x4  __attribute__((ext_vector_type(4)));
typedef unsigned short ushort_t;

// ---------- helpers ----------
__device__ __forceinline__ unsigned short f2h(float f) {
  _Float16 h = (_Float16)f;                  // RNE, native v_cvt_f16_f32
  return __builtin_bit_cast(unsigned short, h);
}
__device__ __forceinline__ unsigned f2h2(float lo, float hi) {
  return (unsigned)f2h(lo) | ((unsigned)f2h(hi) << 16);
}
__device__ __forceinline__ float lin14(int i) {
  double s = 1.0 / 14.0, stop = 1.0 - s;
  double step = (stop - s) / 13.0;
  return (float)((i == 13) ? stop : s + i * step);
}
__device__ __forceinline__ float lin10(int i) {
  double st = 1.0 / 9.0;
  return (float)((i == 9) ? 1.0 : i * st);
}
__device__ __forceinline__ float wave_sum(float v) {
  #pragma unroll
  for (int o = 32; o; o >>= 1) v += __shfl_xor(v, o, 64);
  return v;
}
__device__ __forceinline__ float wave_max(float v) {
  #pragma unroll
  for (int o = 32; o; o >>= 1) v = fmaxf(v, __shfl_xor(v, o, 64));
  return v;
}
__device__ __forceinline__ float blk_sum(float v, float* red) {
  v = wave_sum(v);
  if ((threadIdx.x & 63) == 0) red[threadIdx.x >> 6] = v;
  __syncthreads();
  v = red[0] + red[1] + red[2] + red[3];
  __syncthreads();
  return v;
}
__device__ __forceinline__ float blk_max(float v, float* red) {
  v = wave_max(v);
  if ((threadIdx.x & 63) == 0) red[threadIdx.x >> 6] = v;
  __syncthreads();
  v = fmaxf(fmaxf(red[0], red[1]), fmaxf(red[2], red[3]));
  __syncthreads();
  return v;
}

// ---------- K_F: F[100][196], pos, mus (constants) ----------
__global__ void k_F(float* __restrict__ posg, float* __restrict__ musg,
                    float* __restrict__ Fg) {
  int idx = blockIdx.x * 256 + threadIdx.x;
  if (idx < 196) { posg[2*idx] = lin14(idx / 14); posg[2*idx+1] = lin14(idx % 14); }
  if (idx < 100) { musg[2*idx] = lin10(idx / 10); musg[2*idx+1] = lin10(idx % 10); }
  if (idx < 19600) {
    int k = idx / 196, l = idx % 196;
    float mx = lin10(k / 10), my = lin10(k % 10);
    float px = lin14(l / 14), py = lin14(l % 14);
    double dx = (double)mx - (double)px, dy = (double)my - (double)py;
    double d2 = dx * dx + dy * dy;
    Fg[idx] = (float)(exp(-500.0 * d2) / (6.283185307179586 * 0.001));
  }
}

// ---------- K_A: A = F F^T + 0.5 I (f64) ----------
__global__ void k_A(const float* __restrict__ Fg, double* __restrict__ A) {
  int i = blockIdx.x, j = threadIdx.x;
  if (j < 100) {
    const float* Fi = Fg + i * 196;
    const float* Fj = Fg + j * 196;
    double s = 0.0;
    for (int l = 0; l < 196; ++l) s += (double)Fi[l] * (double)Fj[l];
    if (i == j) s += 0.5;
    A[i * 100 + j] = s;
  }
}

// ---------- K_inv v4: register-resident Gauss-Jordan, f64, SPD, 4 waves ----------
// 250 threads own 4x10 blocks; branch-free rank-1 update via rk[k]=1+1/p,
// ck[k]=p-1 (exact GJ all 4 cases); 2 barriers/iter.
__global__ __launch_bounds__(256) void k_inv(const double* __restrict__ Ag,
                                             double* __restrict__ Ainv) {
  __shared__ double rowraw[100], colraw[100], rkv[100], ckv[100];
  int t = threadIdx.x;
  int rb = t / 10, cb = t % 10;      // t<250: rows [4rb,4rb+4), cols [10cb,10cb+10)
  bool own = t < 250;
  double a[4][10];
  if (own) {
    #pragma unroll
    for (int r = 0; r < 4; ++r)
      #pragma unroll
      for (int c = 0; c < 10; ++c)
        a[r][c] = Ag[(4 * rb + r) * 100 + 10 * cb + c];
  }
  __syncthreads();
  for (int k = 0; k < 100; ++k) {
    int krb = k >> 2, klr = k & 3;
    int kcb = k / 10, klc = k - 10 * kcb;
    if (own && rb == krb) {
      #pragma unroll
      for (int r = 0; r < 4; ++r)
        if (r == klr) {
          #pragma unroll
          for (int c = 0; c < 10; ++c) rowraw[10 * cb + c] = a[r][c];
        }
    }
    if (own && cb == kcb) {
      #pragma unroll
      for (int c = 0; c < 10; ++c)
        if (c == klc) {
          #pragma unroll
          for (int r = 0; r < 4; ++r) colraw[4 * rb + r] = a[r][c];
        }
    }
    __syncthreads();
    if (t < 100) {
      double p = rowraw[k], pinv = 1.0 / p;
      rkv[t] = (t == k) ? 1.0 + pinv : rowraw[t] * pinv;
      ckv[t] = (t == k) ? p - 1.0    : colraw[t];
    }
    __syncthreads();
    if (own) {
      double ckl[4], rkl[10];
      #pragma unroll
      for (int r = 0; r < 4; ++r) ckl[r] = ckv[4 * rb + r];
      #pragma unroll
      for (int c = 0; c < 10; ++c) rkl[c] = rkv[10 * cb + c];
      #pragma unroll
      for (int r = 0; r < 4; ++r)
        #pragma unroll
        for (int c = 0; c < 10; ++c)
          a[r][c] = fma(-ckl[r], rkl[c], a[r][c]);
    }
  }
  if (own) {
    #pragma unroll
    for (int r = 0; r < 4; ++r)
      #pragma unroll
      for (int c = 0; c < 10; ++c)
        Ainv[(4 * rb + r) * 100 + 10 * cb + c] = a[r][c];
  }
}

// ---------- K_G: Gt[n][l] = (F^T @ Ainv)^T ----------
__global__ void k_G(const float* __restrict__ Fg, const double* __restrict__ Ainv,
                    float* __restrict__ Gt) {
  int l = blockIdx.x, n = threadIdx.x;
  if (n < 100) {
    double s = 0.0;
    for (int k = 0; k < 100; ++k) s += (double)Fg[k * 196 + l] * Ainv[k * 100 + n];
    Gt[n * 196 + l] = (float)s;
  }
}

// ---------- K_tr: merged f32->fp16 transposes (z=0: W1->W1t, z=1: Wm->WmT) ----------
__global__ void k_tr(const float* __restrict__ W1, ushort_t* __restrict__ W1t,
                     const float* __restrict__ Wm, ushort_t* __restrict__ WmT) {
  __shared__ float t[32][33];
  int z = blockIdx.z;
  if (z == 0 && blockIdx.x >= 16) return;
  const float* src = z ? Wm : W1;
  ushort_t* dst    = z ? WmT : W1t;
  int NCOL = z ? 2048 : 512;            // src row length
  int n0 = blockIdx.x * 32, k0 = blockIdx.y * 32;
  int tx = threadIdx.x, ty = threadIdx.y;   // 32 x 8
  #pragma unroll
  for (int i = 0; i < 32; i += 8)
    t[ty + i][tx] = src[(size_t)(k0 + ty + i) * NCOL + n0 + tx];
  __syncthreads();
  #pragma unroll
  for (int i = 0; i < 32; i += 8)
    dst[(size_t)(n0 + ty + i) * 1024 + k0 + tx] = f2h(t[tx][ty + i]);
}

// ---------- K_gemm1 v3: logits = relu(x@W1 + b1) @ W2 (fused epilogue) ----------
// r6 post-mortem: lambda-captured prefetch arrays -> scratch spill (WRITE_SIZE
// 6->294MB).  v3: BK=128 single-buffered chunks, plain unrolled code, all
// arrays compile-time-indexed.  8 chunks x 64 MFMA/wave, 2 barriers/chunk
// (15 total vs r5's 33); chunk k+1 global loads issue in regs BEFORE chunk k
// compute (~2000cy MFMA covers ~900cy HBM RTT); 2 blocks/CU (70KB LDS) give
// inter-block overlap of the stage phase (m114).  Pad-136 rows (8x17): bank
// stride 4/row -> all LDS ops at data-volume floor; staging 128-256B/instr.
__global__ __launch_bounds__(256, 2) void k_gemm1(
    const float* __restrict__ x, const ushort_t* __restrict__ W1t,
    const float* __restrict__ b1, const float* __restrict__ W2,
    float* __restrict__ logits) {
  __shared__ __align__(16) ushort_t As[128 * 136];
  __shared__ __align__(16) ushort_t Bs[128 * 136];

  int bid  = blockIdx.x;
  int bid2 = (bid & 7) * 196 + (bid >> 3);       // XCD-contiguous chunks
  int tm = bid2 >> 2, tn = bid2 & 3;
  size_t row0 = (size_t)tm * 128;
  int n0 = tn * 128;
  int tid = threadIdx.x, lane = tid & 63;
  int wid = tid >> 6, wm = wid >> 1, wn = wid & 1;

  // A: 8 lanes/row, 4 row-passes of 32; cols (tid&7)*4 + j*32 (128B/instr/8lanes)
  const float* xq = x + (row0 + (tid >> 3)) * 1024 + ((tid & 7) << 2);
  int soa = (tid >> 3) * 136 + ((tid & 7) << 2);
  // B: 16 lanes/row, 8 row-passes of 16; cols (tid&15)*8 (256B/instr/16lanes)
  const ushort_t* wq = W1t + (size_t)(n0 + (tid >> 4)) * 1024 + ((tid & 15) << 3);
  int sob = (tid >> 4) * 136 + ((tid & 15) << 3);

  int aro = (wm * 64 + (lane & 15)) * 136 + ((lane >> 4) << 3);
  int bro = (wn * 64 + (lane & 15)) * 136 + ((lane >> 4) << 3);

  f32x4 acc[4][4] = {};
  float4 ax[4][4];
  uint4  bw[8];

#define G1_ISSUE(kc)                                                          \
  do {                                                                        \
    _Pragma("unroll") for (int p = 0; p < 4; ++p)                             \
      _Pragma("unroll") for (int j = 0; j < 4; ++j)                           \
        ax[p][j] = *(const float4*)(xq + (kc) * 128 + p * 32 * 1024 + j * 32);\
    _Pragma("unroll") for (int p = 0; p < 8; ++p)                             \
      bw[p] = *(const uint4*)(wq + (kc) * 128 + p * 16 * 1024);               \
  } while (0)

#define G1_WRITE()                                                            \
  do {                                                                        \
    _Pragma("unroll") for (int p = 0; p < 4; ++p)                             \
      _Pragma("unroll") for (int j = 0; j < 4; ++j) {                         \
        uint2 w2_;                                                            \
        w2_.x = f2h2(ax[p][j].x, ax[p][j].y);                                 \
        w2_.y = f2h2(ax[p][j].z, ax[p][j].w);                                 \
        *(uint2*)&As[soa + p * 32 * 136 + j * 32] = w2_;                      \
      }                                                                       \
    _Pragma("unroll") for (int p = 0; p < 8; ++p)                             \
      *(uint4*)&Bs[sob + p * 16 * 136] = bw[p];                               \
  } while (0)

#define G1_MMAC()                                                             \
  do {                                                                        \
    _Pragma("unroll") for (int s = 0; s < 4; ++s) {                           \
      half8v af[4], bf[4];                                                    \
      _Pragma("unroll") for (int i = 0; i < 4; ++i)                           \
        af[i] = *(const half8v*)&As[aro + i * 16 * 136 + s * 32];             \
      _Pragma("unroll") for (int i = 0; i < 4; ++i)                           \
        bf[i] = *(const half8v*)&Bs[bro + i * 16 * 136 + s * 32];             \
      _Pragma("unroll") for (int i = 0; i < 4; ++i)                           \
        _Pragma("unroll") for (int j = 0; j < 4; ++j)                         \
          acc[i][j] = __builtin_amdgcn_mfma_f32_16x16x32_f16(                 \
              af[i], bf[j], acc[i][j], 0, 0, 0);                              \
    }                                                                         \
  } while (0)

  G1_ISSUE(0);
  G1_WRITE();
  __syncthreads();
  #pragma unroll 1
  for (int kc = 1; kc < 8; ++kc) {
    G1_ISSUE(kc);      // loads for kc in flight while computing kc-1
    G1_MMAC();         // compute chunk kc-1 from LDS
    __syncthreads();   // all waves done reading LDS
    G1_WRITE();        // store chunk kc
    __syncthreads();   // chunk kc visible
  }
  G1_MMAC();           // last chunk

#undef G1_ISSUE
#undef G1_WRITE
#undef G1_MMAC

  // fused epilogue: logits partial = sum_n relu(acc + b1[n]) * W2[n]
  int cbase = n0 + wn * 64 + (lane & 15);
  float b1v[4], w2v[4];
  #pragma unroll
  for (int j = 0; j < 4; ++j) { b1v[j] = b1[cbase + j * 16]; w2v[j] = W2[cbase + j * 16]; }
  float part[4][4];
  #pragma unroll
  for (int i = 0; i < 4; ++i)
    #pragma unroll
    for (int q = 0; q < 4; ++q) {
      float s = 0.f;
      #pragma unroll
      for (int j = 0; j < 4; ++j) {
        float h = acc[i][j][q] + b1v[j];
        s += fmaxf(h, 0.f) * w2v[j];
      }
      part[i][q] = s;
    }
  #pragma unroll
  for (int off = 1; off < 16; off <<= 1)
    #pragma unroll
    for (int i = 0; i < 4; ++i)
      #pragma unroll
      for (int q = 0; q < 4; ++q)
        part[i][q] += __shfl_xor(part[i][q], off, 64);
  if ((lane & 15) == 0) {
    int rbase = (int)row0 + wm * 64 + ((lane >> 4) << 2);
    #pragma unroll
    for (int i = 0; i < 4; ++i)
      #pragma unroll
      for (int q = 0; q < 4; ++q)
        atomicAdd(&logits[rbase + i * 16 + q], part[i][q]);
  }
}

// ---------- K_batch: softmax, mu, Sigma, Sinv, r, g = Gt^T@r ----------
__global__ __launch_bounds__(256) void k_batch(
    const float* __restrict__ logits, const unsigned char* __restrict__ mask,
    const float* __restrict__ b2, const float* __restrict__ pos,
    const float* __restrict__ mus, const float* __restrict__ Gt,
    float* __restrict__ g_out) {
  __shared__ float red[4];
  __shared__ float rsh[100];
  int b = blockIdx.x, tid = threadIdx.x;
  bool act = tid < 196;
  float lg = -1e30f;
  if (act) {
    lg = logits[b * 196 + tid] + b2[0];
    if (mask[b * 196 + tid]) lg = -1e9f;
  }
  float m = blk_max(lg, red);
  float e = act ? expf(lg - m) : 0.f;
  float Z = blk_sum(e, red);
  float pv = e / Z;
  float px = act ? pos[2 * tid] : 0.f, py = act ? pos[2 * tid + 1] : 0.f;
  float mux = blk_sum(pv * px, red);
  float muy = blk_sum(pv * py, red);
  float dx = px - mux, dy = py - muy;
  float sxx = blk_sum(pv * dx * dx, red);
  float sxy = blk_sum(pv * dx * dy, red);
  float syy = blk_sum(pv * dy * dy, red);
  float aa = (sxx + 1e-6f) + 1e-3f;
  float bb = sxy;
  float dd = (syy + 1e-6f) + 1e-3f;
  float det = aa * dd - bb * bb;
  float scale = 1.f / (6.2831853071795864f * sqrtf(det));
  if (tid < 100) {
    float dmx = mux - mus[2 * tid], dmy = muy - mus[2 * tid + 1];
    float quad = (dd * dmx * dmx - 2.f * bb * dmx * dmy + aa * dmy * dmy) / det;
    rsh[tid] = expf(-0.5f * quad) * scale;
  }
  __syncthreads();
  if (act) {
    float s = 0.f;
    #pragma unroll 4
    for (int n = 0; n < 100; ++n) s = fmaf(Gt[n * 196 + tid], rsh[n], s);
    g_out[b * 196 + tid] = s;
  }
}

// ---------- K_ctx v2: ctxh[b,d] = (fp16) sum_l x[b,l,d] * g[b,l] ----------
// G13: float4 loads (16B/lane, 1KB/wave-instr) instead of 4B/lane scalar.
// One block per b; 256 threads x 4 d each; 8B fp16 packed store.
// HBM floor: 205MB / 6.3TB/s = 33us.
__global__ __launch_bounds__(256) void k_ctx(const float* __restrict__ x,
                                             const float* __restrict__ g,
                                             ushort_t* __restrict__ ctxh) {
  int b = blockIdx.x, tid = threadIdx.x;
  __shared__ float gs[196];
  if (tid < 196) gs[tid] = g[b * 196 + tid];
  __syncthreads();
  int d = tid << 2;
  const float* xp = x + (size_t)b * 200704 + d;
  float a0 = 0.f, a1 = 0.f, a2 = 0.f, a3 = 0.f;
  #pragma unroll 4
  for (int l = 0; l < 196; ++l) {
    float4 v = *(const float4*)(xp + (size_t)l * 1024);
    float gl = gs[l];
    a0 = fmaf(v.x, gl, a0); a1 = fmaf(v.y, gl, a1);
    a2 = fmaf(v.z, gl, a2); a3 = fmaf(v.w, gl, a3);
  }
  uint2 o; o.x = f2h2(a0, a1); o.y = f2h2(a2, a3);
  *(uint2*)&ctxh[(size_t)b * 1024 + d] = o;
}

// ---------- K_out2: out = ctxh @ WmT^T + bm   (fp16 MFMA, 64x128 tile, BK=32) ----------
__global__ __launch_bounds__(256, 2) void k_out2(
    const ushort_t* __restrict__ ctxh, const ushort_t* __restrict__ WmT,
    const float* __restrict__ bm, float* __restrict__ out) {
  __shared__ __align__(16) ushort_t As[2][64 * 40];
  __shared__ __align__(16) ushort_t Bs[2][128 * 40];
  int n0 = blockIdx.x * 128;
  int m0 = blockIdx.y * 64;
  int tid = threadIdx.x, lane = tid & 63;
  int wid = tid >> 6, wm = wid >> 1, wn = wid & 1;

  int arow = tid >> 2, aseg = (tid & 3) << 3;
  const ushort_t* ap = ctxh + (m0 + arow) * 1024 + aseg;
  int aso = arow * 40 + aseg;
  int brow = tid >> 1, bsh = (tid & 1) << 4;
  const ushort_t* bp = WmT + (size_t)(n0 + brow) * 1024 + bsh;
  int bso = brow * 40 + bsh;

  int aro = (wm * 32 + (lane & 15)) * 40 + ((lane >> 4) << 3);
  int bro = (wn * 64 + (lane & 15)) * 40 + ((lane >> 4) << 3);

  f32x4 acc[2][4] = {};
  uint4 a4, b4[2];
  a4 = *(const uint4*)ap;
  b4[0] = *(const uint4*)bp; b4[1] = *(const uint4*)(bp + 8);
  *(uint4*)&As[0][aso] = a4;
  *(uint4*)&Bs[0][bso] = b4[0]; *(uint4*)&Bs[0][bso + 8] = b4[1];
  __syncthreads();

  int cur = 0;
  for (int ks = 0; ks < 32; ++ks) {
    if (ks < 31) {
      a4 = *(const uint4*)(ap + (ks + 1) * 32);
      b4[0] = *(const uint4*)(bp + (ks + 1) * 32);
      b4[1] = *(const uint4*)(bp + (ks + 1) * 32 + 8);
    }
    half8v af[2], bf[4];
    #pragma unroll
    for (int i = 0; i < 2; ++i) af[i] = *(const half8v*)&As[cur][aro + i * 16 * 40];
    #pragma unroll
    for (int j = 0; j < 4; ++j) bf[j] = *(const half8v*)&Bs[cur][bro + j * 16 * 40];
    #pragma unroll
    for (int i = 0; i < 2; ++i)
      #pragma unroll
      for (int j = 0; j < 4; ++j)
        acc[i][j] = __builtin_amdgcn_mfma_f32_16x16x32_f16(af[i], bf[j], acc[i][j], 0, 0, 0);
    if (ks < 31) {
      *(uint4*)&As[cur ^ 1][aso] = a4;
      *(uint4*)&Bs[cur ^ 1][bso] = b4[0]; *(uint4*)&Bs[cur ^ 1][bso + 8] = b4[1];
    }
    __syncthreads();
    cur ^= 1;
  }

  int rbase = m0 + wm * 32 + ((lane >> 4) << 2);
  int cbase = n0 + wn * 64 + (lane & 15);
  #pragma unroll
  for (int j = 0; j < 4; ++j) {
    float bmv = bm[cbase + j * 16];
    #pragma unroll
    for (int i = 0; i < 2; ++i)
      #pragma unroll
      for (int q = 0; q < 4; ++q)
        out[(size_t)(rbase + i * 16 + q) * 2048 + cbase + j * 16] = acc[i][j][q] + bmv;
  }
}

// ---------- launch ----------
extern "C" void kernel_launch(void* const* d_in, const int* in_sizes, int n_in,
                              void* d_out, int out_size, void* d_ws, size_t ws_size,
                              hipStream_t stream) {
  const float* x  = (const float*)d_in[0];
  const unsigned char* xmask = (const unsigned char*)d_in[1];
  const float* W1 = (const float*)d_in[2];
  const float* b1 = (const float*)d_in[3];
  const float* W2 = (const float*)d_in[4];
  const float* b2 = (const float*)d_in[5];
  const float* Wm = (const float*)d_in[6];
  const float* bm = (const float*)d_in[7];
  float* out = (float*)d_out;

  char* ws = (char*)d_ws;
  float*    Fg     = (float*)(ws + 0);          // 78400 B
  double*   Ainv   = (double*)(ws + 78400);     // 80000 B
  double*   Atmp   = (double*)(ws + 158400);    // 80000 B
  float*    posg   = (float*)(ws + 238400);     // 1568 B
  float*    musg   = (float*)(ws + 239968);     // 800 B
  float*    Gt     = (float*)(ws + 240768);     // 78400 B
  float*    logits = (float*)(ws + 319168);     // 200704 B
  float*    gbuf   = (float*)(ws + 519872);     // 200704 B
  ushort_t* ctxh   = (ushort_t*)(ws + 720576);  // 524288 B
  ushort_t* W1t    = (ushort_t*)(ws + 1244864); // 1048576 B
  ushort_t* WmT    = (ushort_t*)(ws + 2293440); // 4194304 B  (total ~6.2 MB)

  k_F<<<77, 256, 0, stream>>>(posg, musg, Fg);
  k_A<<<100, 128, 0, stream>>>(Fg, Atmp);
  k_inv<<<1, 256, 0, stream>>>(Atmp, Ainv);
  k_G<<<196, 128, 0, stream>>>(Fg, Ainv, Gt);
  k_tr<<<dim3(64, 32, 2), dim3(32, 8), 0, stream>>>(W1, W1t, Wm, WmT);
  hipMemsetAsync(logits, 0, 200704, stream);
  k_gemm1<<<1568, 256, 0, stream>>>(x, W1t, b1, W2, logits);
  k_batch<<<256, 256, 0, stream>>>(logits, xmask, b2, posg, musg, Gt, gbuf);
  k_ctx<<<256, 256, 0, stream>>>(x, gbuf, ctxh);
  k_out2<<<dim3(16, 4), 256, 0, stream>>>(ctxh, WmT, bm, out);
}